// Round 4
// baseline (833.768 us; speedup 1.0000x reference)
//
#include <hip/hip_runtime.h>

#define NTRAIN 32768
#define NTEST  4096
#define DIM    64
#define KSEL   32
#define NLAB   1000
#define SAMPLE 2048
#define PRANK  16
#define CAP    768
#define POOLCAP 1600
#define WCOEF  0.02f   // >= 2^-7 (bf16 RN product err) * 2.5x safety

using short8 = __attribute__((ext_vector_type(8))) short;
using f32x4  = __attribute__((ext_vector_type(4))) float;
typedef unsigned short u16;

// monotone float -> uint mapping (preserves total order incl. negatives)
__device__ __forceinline__ unsigned f2u(float f){
  unsigned b = __float_as_uint(f);
  return (b & 0x80000000u) ? ~b : (b | 0x80000000u);
}
__device__ __forceinline__ float u2f(unsigned u){
  unsigned b = (u & 0x80000000u) ? (u & 0x7fffffffu) : ~u;
  return __uint_as_float(b);
}
// fp32 -> bf16 round-to-nearest-even (manual, header-independent)
__device__ __forceinline__ u16 f2b(float x){
  unsigned u = __float_as_uint(x);
  return (u16)((u + 0x7fffu + ((u >> 16) & 1u)) >> 16);
}

struct Sel {
  unsigned hist[2048];
  unsigned wsum[4];
  unsigned sB, sLess, sU;
  int sNeed;
};

// exact value of the rank-th smallest key (1-based) among keys[0..n). n>=rank.
__device__ unsigned radix_select(const unsigned* __restrict__ keys, int n,
                                 unsigned rank, Sel* s, int t, int* needOut)
{
  const int lane = t & 63, wid = t >> 6;
  unsigned target = rank, pref = 0;
  for (int lev = 0; lev < 3; ++lev){
    const int nb    = (lev == 2) ? 1024 : 2048;
    const int shift = (lev == 0) ? 21 : (lev == 1 ? 10 : 0);
    for (int q = t; q < nb; q += 256) s->hist[q] = 0;
    __syncthreads();
    for (int i = t; i < n; i += 256){
      unsigned u = keys[i];
      bool ok = (lev == 0) ? true
              : (lev == 1) ? ((u >> 21) == pref)
                           : ((u >> 10) == pref);
      if (ok) atomicAdd(&s->hist[(u >> shift) & (unsigned)(nb - 1)], 1u);
    }
    __syncthreads();
    const int g = nb / 256;
    unsigned sl = 0;
#pragma unroll
    for (int k = 0; k < 8; ++k) if (k < g) sl += s->hist[t*g + k];
    unsigned x = sl;
#pragma unroll
    for (int ofs = 1; ofs < 64; ofs <<= 1){
      unsigned v = __shfl_up(x, (unsigned)ofs, 64);
      if (lane >= ofs) x += v;
    }
    if (lane == 63) s->wsum[wid] = x;
    __syncthreads();
    unsigned woff = 0;
#pragma unroll
    for (int w = 0; w < 4; ++w) if (w < wid) woff += s->wsum[w];
    unsigned incl = x + woff;
    unsigned excl = incl - sl;
    if (excl < target && target <= incl){
      unsigned cum = excl; int b = t*g;
      while (cum + s->hist[b] < target){ cum += s->hist[b]; ++b; }
      s->sB = (unsigned)b; s->sLess = cum;
    }
    __syncthreads();
    unsigned B = s->sB, cl = s->sLess;
    target -= cl;
    if      (lev == 0) pref = B;
    else if (lev == 1) pref = (pref << 11) | B;
    else if (t == 0){ s->sU = (pref << 10) | B; s->sNeed = (int)target; }
  }
  __syncthreads();
  *needOut = s->sNeed;
  return s->sU;
}

// exact top-KSEL among (ku,ki)[0..n) by (key asc, idx asc). n>=KSEL. writes selI.
__device__ void select32(const unsigned* ku, const unsigned* ki, int n,
                         Sel* s, unsigned* tieI, unsigned* selI,
                         int* selCnt, int* tieCnt, int t)
{
  int need;
  unsigned ustar = radix_select(ku, n, KSEL, s, t, &need);
  if (t == 0){ *selCnt = 0; *tieCnt = 0; }
  __syncthreads();
  for (int i = t; i < n; i += 256){
    unsigned u = ku[i];
    if (u < ustar){ int p = atomicAdd(selCnt, 1); if (p < 40) selI[p] = ki[i]; }
    else if (u == ustar){ int p = atomicAdd(tieCnt, 1); if (p < 256) tieI[p] = ki[i]; }
  }
  __syncthreads();
  int nT = *tieCnt; if (nT > 256) nT = 256;
  if (t < nT){
    unsigned my = tieI[t]; int r = 0;
    for (int k = 0; k < nT; ++k) r += (tieI[k] < my) ? 1 : 0;
    if (r < need){ int p = atomicAdd(selCnt, 1); if (p < 40) selI[p] = my; }
  }
  __syncthreads();
}

// ---- prep: x_train -> bf16 row-major + hb2 = 0.5*||b||^2 + max b2 ----
__global__ __launch_bounds__(256) void prep(const float* __restrict__ xtr,
        u16* __restrict__ xtr16, float* __restrict__ hb2,
        unsigned* __restrict__ maxb2u)
{
  int j = blockIdx.x*256 + threadIdx.x;
  const float4* rp = (const float4*)(xtr + (size_t)j*DIM);
  u16* orow = xtr16 + (size_t)j*DIM;
  float s = 0.f;
#pragma unroll
  for (int q = 0; q < 16; ++q){
    float4 w = rp[q];
    uint2 pk;
    pk.x = (unsigned)f2b(w.x) | ((unsigned)f2b(w.y) << 16);
    pk.y = (unsigned)f2b(w.z) | ((unsigned)f2b(w.w) << 16);
    *(uint2*)(orow + q*4) = pk;
    s = fmaf(w.x,w.x,s); s = fmaf(w.y,w.y,s);
    s = fmaf(w.z,w.z,s); s = fmaf(w.w,w.w,s);
  }
  hb2[j] = 0.5f * s;
  atomicMax(maxb2u, __float_as_uint(s));   // s > 0 -> uint order == float order
}

// ---- prepT: x_test -> bf16 row-major + a2 ----
__global__ __launch_bounds__(256) void prepT(const float* __restrict__ xtst,
        u16* __restrict__ xtst16, float* __restrict__ a2)
{
  int m = blockIdx.x*256 + threadIdx.x;
  const float4* rp = (const float4*)(xtst + (size_t)m*DIM);
  u16* orow = xtst16 + (size_t)m*DIM;
  float s = 0.f;
#pragma unroll
  for (int q = 0; q < 16; ++q){
    float4 w = rp[q];
    uint2 pk;
    pk.x = (unsigned)f2b(w.x) | ((unsigned)f2b(w.y) << 16);
    pk.y = (unsigned)f2b(w.z) | ((unsigned)f2b(w.w) << 16);
    *(uint2*)(orow + q*4) = pk;
    s = fmaf(w.x,w.x,s); s = fmaf(w.y,w.y,s);
    s = fmaf(w.z,w.z,s); s = fmaf(w.w,w.w,s);
  }
  a2[m] = s;
}

// ---- pre: per-test threshold via MFMA keys over first SAMPLE train pts ----
// key' = hb2[j] - dot (monotone-equivalent to squared distance)
__global__ __launch_bounds__(256) void pre_kernel(const u16* __restrict__ xtr16,
        const u16* __restrict__ xtst16, const float* __restrict__ hb2,
        const float* __restrict__ a2, const unsigned* __restrict__ maxb2u,
        float* __restrict__ Tfp, float* __restrict__ thrW)
{
  __shared__ unsigned keysL[8][SAMPLE+4];   // +4 pad: conflict-free row stride
  __shared__ Sel ss;

  const int t = threadIdx.x, lane = t & 63, w = t >> 6;
  const int m0 = blockIdx.x * 16;
  const int oprow = lane & 15, kgrp = lane >> 4;

  const u16* ap = xtst16 + (size_t)(m0 + oprow)*DIM + kgrp*8;
  short8 af0 = *(const short8*)ap;
  short8 af1 = *(const short8*)(ap + 32);

  const float mb = __uint_as_float(*maxb2u);

  for (int ph = 0; ph < 2; ++ph){
    __syncthreads();
    for (int jt = 0; jt < SAMPLE/64; ++jt){     // 32 tiles per wave
      int j0 = w*(SAMPLE/4) + jt*16;
      const u16* bp = xtr16 + (size_t)(j0 + oprow)*DIM + kgrp*8;
      short8 b0 = *(const short8*)bp;
      short8 b1 = *(const short8*)(bp + 32);
      f32x4 acc = {0.f,0.f,0.f,0.f};
      acc = __builtin_amdgcn_mfma_f32_16x16x32_bf16(af0, b0, acc, 0,0,0);
      acc = __builtin_amdgcn_mfma_f32_16x16x32_bf16(af1, b1, acc, 0,0,0);
      float h = hb2[j0 + oprow];
#pragma unroll
      for (int r = 0; r < 4; ++r){
        int row = kgrp*4 + r;                   // C row = test within tile
        if ((row >> 3) == ph)
          keysL[row & 7][j0 + oprow] = f2u(h - acc[r]);
      }
    }
    __syncthreads();
    for (int r = 0; r < 8; ++r){
      int need;
      unsigned ustar = radix_select(&keysL[r][0], SAMPLE, PRANK, &ss, t, &need);
      if (t == 0){
        int m = m0 + ph*8 + r;
        float Tf = u2f(ustar);
        Tfp[m]  = Tf;
        thrW[m] = Tf + WCOEF * sqrtf(a2[m] * mb);
      }
    }
  }
}

// ---- kernel A: MFMA filter. Zero LDS, zero barriers in the main loop. ----
__global__ __launch_bounds__(256, 4) void knnA(const u16* __restrict__ xtr16,
        const u16* __restrict__ xtst16, const float* __restrict__ hb2,
        const float* __restrict__ thrW, unsigned* __restrict__ cnt,
        unsigned* __restrict__ cand)
{
  const int t = threadIdx.x, lane = t & 63, w = t >> 6;
  const int bid = blockIdx.x;
  const int jc  = bid & 31;           // 32 j-chunks of 1024 (bid%8 -> XCD locality)
  const int mg  = bid >> 5;           // 32 m-blocks of 128 tests
  const int m0  = mg*128 + w*32;      // wave owns 32 tests (2 MFMA subtiles)
  const int oprow = lane & 15, kgrp = lane >> 4;

  const u16* ap = xtst16 + (size_t)(m0 + oprow)*DIM + kgrp*8;
  short8 a00 = *(const short8*)ap;
  short8 a01 = *(const short8*)(ap + 32);
  short8 a10 = *(const short8*)(ap + 16*DIM);
  short8 a11 = *(const short8*)(ap + 16*DIM + 32);

  float thr0[4], thr1[4];
#pragma unroll
  for (int r = 0; r < 4; ++r){
    thr0[r] = thrW[m0 + kgrp*4 + r];
    thr1[r] = thrW[m0 + 16 + kgrp*4 + r];
  }
  float tmax0 = fmaxf(fmaxf(thr0[0],thr0[1]), fmaxf(thr0[2],thr0[3]));
  float tmax1 = fmaxf(fmaxf(thr1[0],thr1[1]), fmaxf(thr1[2],thr1[3]));

  const u16* bp = xtr16 + (size_t)(jc*1024 + oprow)*DIM + kgrp*8;
  const float* hp = hb2 + jc*1024 + oprow;

#pragma unroll 2
  for (int jt = 0; jt < 64; ++jt){
    short8 b0 = *(const short8*)bp;
    short8 b1 = *(const short8*)(bp + 32);
    float h = *hp;
    f32x4 c0 = {0.f,0.f,0.f,0.f}, c1 = {0.f,0.f,0.f,0.f};
    c0 = __builtin_amdgcn_mfma_f32_16x16x32_bf16(a00, b0, c0, 0,0,0);
    c0 = __builtin_amdgcn_mfma_f32_16x16x32_bf16(a01, b1, c0, 0,0,0);
    c1 = __builtin_amdgcn_mfma_f32_16x16x32_bf16(a10, b0, c1, 0,0,0);
    c1 = __builtin_amdgcn_mfma_f32_16x16x32_bf16(a11, b1, c1, 0,0,0);
    int j = jc*1024 + jt*16 + oprow;
    // candidate iff (hb2 - dot) < thrW  <=>  dot + thrW > hb2 (margin >> rounding)
    float mx0 = fmaxf(fmaxf(c0[0],c0[1]), fmaxf(c0[2],c0[3]));
    if (mx0 + tmax0 > h){
#pragma unroll
      for (int r = 0; r < 4; ++r) if (c0[r] + thr0[r] > h){
        int m = m0 + kgrp*4 + r;
        unsigned p = atomicAdd(&cnt[m], 1u);
        if (p < CAP) cand[(size_t)m*CAP + p] = (unsigned)j;
      }
    }
    float mx1 = fmaxf(fmaxf(c1[0],c1[1]), fmaxf(c1[2],c1[3]));
    if (mx1 + tmax1 > h){
#pragma unroll
      for (int r = 0; r < 4; ++r) if (c1[r] + thr1[r] > h){
        int m = m0 + 16 + kgrp*4 + r;
        unsigned p = atomicAdd(&cnt[m], 1u);
        if (p < CAP) cand[(size_t)m*CAP + p] = (unsigned)j;
      }
    }
    bp += 16*DIM; hp += 16;
  }
}

// ---- kernel B: exact fp32 re-rank of candidates with verification ----
__global__ __launch_bounds__(256) void knnB(const float* __restrict__ x_train,
        const float* __restrict__ hb2, const float* __restrict__ x_test,
        const int* __restrict__ y_train, const float* __restrict__ w_train,
        const float* __restrict__ Tfp, const unsigned* __restrict__ cnt,
        const unsigned* __restrict__ cand, int* __restrict__ out)
{
  __shared__ unsigned ku[POOLCAP], ki[POOLCAP];
  __shared__ unsigned chunkKeys[1024];
  __shared__ Sel ss;
  __shared__ unsigned tieI[256];
  __shared__ unsigned selI[40];
  __shared__ int selCnt, tieCnt, poolCnt, nBelow;
  __shared__ float votes[NLAB];

  const int t = threadIdx.x, m = blockIdx.x;
  float a[DIM];
  const float4* am = (const float4*)(x_test + (size_t)m*DIM);
#pragma unroll
  for (int q = 0; q < 16; ++q){
    float4 v = am[q];
    a[4*q]=v.x; a[4*q+1]=v.y; a[4*q+2]=v.z; a[4*q+3]=v.w;
  }
  const float Tf = Tfp[m];
  const unsigned c = cnt[m];

  if (t == 0) nBelow = 0;
  __syncthreads();

  bool ok = false;
  if (c >= KSEL && c <= CAP){
    for (int i = t; i < (int)c; i += 256){
      unsigned j = cand[(size_t)m*CAP + i];
      const float4* rp = (const float4*)(x_train + (size_t)j*DIM);
      float s = 0.f;
#pragma unroll
      for (int q = 0; q < 16; ++q){
        float4 v = rp[q];
        s = fmaf(a[4*q],v.x,s); s = fmaf(a[4*q+1],v.y,s);
        s = fmaf(a[4*q+2],v.z,s); s = fmaf(a[4*q+3],v.w,s);
      }
      float kf = hb2[j] - s;
      ku[i] = f2u(kf); ki[i] = j;
      if (kf < Tf) atomicAdd(&nBelow, 1);
    }
    __syncthreads();
    ok = (nBelow >= KSEL);   // guarantees global top-32 is inside candidates
    if (ok) select32(ku, ki, (int)c, &ss, tieI, selI, &selCnt, &tieCnt, t);
  }

  if (!ok){
    // exact full scan (rare / safety net): chunk top-32 pooling
    if (t == 0) poolCnt = 0;
    __syncthreads();
    for (int ch = 0; ch < NTRAIN/1024; ++ch){
      const int j0 = ch*1024;
      for (int q = 0; q < 4; ++q){
        int j = j0 + q*256 + t;
        const float4* rp = (const float4*)(x_train + (size_t)j*DIM);
        float s = 0.f;
#pragma unroll
        for (int qq = 0; qq < 16; ++qq){
          float4 v = rp[qq];
          s = fmaf(a[4*qq],v.x,s); s = fmaf(a[4*qq+1],v.y,s);
          s = fmaf(a[4*qq+2],v.z,s); s = fmaf(a[4*qq+3],v.w,s);
        }
        chunkKeys[q*256 + t] = f2u(hb2[j] - s);
      }
      __syncthreads();
      int need;
      unsigned ustar = radix_select(chunkKeys, 1024, KSEL, &ss, t, &need);
      for (int q = 0; q < 4; ++q){
        unsigned u = chunkKeys[q*256 + t];
        if (u <= ustar){
          int p = atomicAdd(&poolCnt, 1);
          if (p < POOLCAP){ ku[p] = u; ki[p] = (unsigned)(j0 + q*256 + t); }
        }
      }
      __syncthreads();
    }
    int n = poolCnt; if (n > POOLCAP) n = POOLCAP;
    select32(ku, ki, n, &ss, tieI, selI, &selCnt, &tieCnt, t);
  }

  // weighted vote over 1000 labels
  for (int q = t; q < NLAB; q += 256) votes[q] = 0.f;
  __syncthreads();
  int nSel = selCnt; if (nSel > KSEL) nSel = KSEL;
  if (t < nSel){
    unsigned j = selI[t];
    atomicAdd(&votes[y_train[j]], w_train[j]);
  }
  __syncthreads();

  // argmax, lowest label wins ties
  float* rv = (float*)ss.hist;
  int*   rl = (int*)(ss.hist + 256);
  float bv = -1.f; int bl = 0;
  for (int l = t; l < NLAB; l += 256){
    float v = votes[l];
    if (v > bv){ bv = v; bl = l; }
  }
  rv[t] = bv; rl[t] = bl;
  __syncthreads();
  for (int sred = 128; sred > 0; sred >>= 1){
    if (t < sred){
      if (rv[t+sred] > rv[t] || (rv[t+sred] == rv[t] && rl[t+sred] < rl[t])){
        rv[t] = rv[t+sred]; rl[t] = rl[t+sred];
      }
    }
    __syncthreads();
  }
  if (t == 0) out[m] = rl[0];
}

// ---- legacy (direct-read path): used only if ws too small ----
__global__ __launch_bounds__(256) void knn_legacy(
    const float* __restrict__ x_train, const float* __restrict__ x_test,
    const int* __restrict__ y_train, const float* __restrict__ w_train,
    int* __restrict__ out)
{
  __shared__ unsigned keys[16384];
  __shared__ Sel ss;
  __shared__ unsigned candU[64];
  __shared__ unsigned candI[64];
  __shared__ unsigned tieI[256];
  __shared__ int nCand, nTie;
  __shared__ float rv[256]; __shared__ int rl[256];

  float* votes = (float*)ss.hist;
  const int t = threadIdx.x;
  const int m = blockIdx.x;

  float a[DIM];
  const float* am = x_test + (size_t)m * DIM;
#pragma unroll
  for (int d = 0; d < DIM; ++d) a[d] = am[d];

  if (t == 0) nCand = 0;

  for (int h = 0; h < 2; ++h){
    __syncthreads();
    for (int i = 0; i < 64; ++i){
      int j = h*16384 + i*256 + t;
      const float4* bp = (const float4*)(x_train + (size_t)j * DIM);
      float s = 0.f;
#pragma unroll
      for (int q = 0; q < 16; ++q){
        float4 v = bp[q];
        float e0 = a[4*q]   - v.x, e1 = a[4*q+1] - v.y;
        float e2 = a[4*q+2] - v.z, e3 = a[4*q+3] - v.w;
        s = fmaf(e0,e0,s); s = fmaf(e1,e1,s); s = fmaf(e2,e2,s); s = fmaf(e3,e3,s);
      }
      keys[i*256 + t] = f2u(s);
    }
    __syncthreads();

    int need;
    unsigned ustar = radix_select(keys, 16384, KSEL, &ss, t, &need);
    if (t == 0) nTie = 0;
    __syncthreads();

    for (int i = 0; i < 64; ++i){
      unsigned u   = keys[i*256 + t];
      unsigned idx = (unsigned)(h*16384 + i*256 + t);
      if (u < ustar){
        int p = atomicAdd(&nCand, 1);
        if (p < 64){ candU[p] = u; candI[p] = idx; }
      } else if (u == ustar){
        int p = atomicAdd(&nTie, 1);
        if (p < 256) tieI[p] = idx;
      }
    }
    __syncthreads();
    int nT = nTie; if (nT > 256) nT = 256;
    if (t < nT){
      unsigned my = tieI[t]; int r = 0;
      for (int k = 0; k < nT; ++k) r += (tieI[k] < my) ? 1 : 0;
      if (r < need){
        int p = atomicAdd(&nCand, 1);
        if (p < 64){ candU[p] = ustar; candI[p] = my; }
      }
    }
    __syncthreads();
  }

  for (int q = t; q < NLAB; q += 256) votes[q] = 0.f;
  __syncthreads();
  int nC = nCand; if (nC > 64) nC = 64;
  if (t < nC){
    unsigned mu = candU[t], mi = candI[t];
    int r = 0;
    for (int k = 0; k < nC; ++k){
      unsigned kku = candU[k], kki = candI[k];
      r += (kku < mu || (kku == mu && kki < mi)) ? 1 : 0;
    }
    if (r < KSEL){
      int lab = y_train[mi];
      atomicAdd(&votes[lab], w_train[mi]);
    }
  }
  __syncthreads();

  float bv = -1.f; int bl = 0;
  for (int l = t; l < NLAB; l += 256){
    float v = votes[l];
    if (v > bv){ bv = v; bl = l; }
  }
  rv[t] = bv; rl[t] = bl;
  __syncthreads();
  for (int s = 128; s > 0; s >>= 1){
    if (t < s){
      if (rv[t+s] > rv[t] || (rv[t+s] == rv[t] && rl[t+s] < rl[t])){
        rv[t] = rv[t+s]; rl[t] = rl[t+s];
      }
    }
    __syncthreads();
  }
  if (t == 0) out[m] = rl[0];
}

extern "C" void kernel_launch(void* const* d_in, const int* in_sizes, int n_in,
                              void* d_out, int out_size, void* d_ws, size_t ws_size,
                              hipStream_t stream)
{
  (void)in_sizes; (void)n_in; (void)out_size;
  const float* x_train = (const float*)d_in[0];
  const int*   y_train = (const int*)  d_in[1];
  const float* x_test  = (const float*)d_in[2];
  const float* w_train = (const float*)d_in[3];
  int* out = (int*)d_out;

  char* p = (char*)d_ws;
  u16*      xtr16  = (u16*)p;       p += (size_t)NTRAIN*DIM*2;
  u16*      xtst16 = (u16*)p;       p += (size_t)NTEST*DIM*2;
  float*    hb2    = (float*)p;     p += (size_t)NTRAIN*4;
  float*    a2     = (float*)p;     p += (size_t)NTEST*4;
  float*    Tfp    = (float*)p;     p += (size_t)NTEST*4;
  float*    thrW   = (float*)p;     p += (size_t)NTEST*4;
  unsigned* cnt    = (unsigned*)p;  p += (size_t)NTEST*4;
  unsigned* maxb2u = (unsigned*)p;  p += 256;
  unsigned* cand   = (unsigned*)p;  p += (size_t)NTEST*CAP*4;
  size_t need = (size_t)(p - (char*)d_ws);

  if (ws_size >= need){
    hipMemsetAsync(cnt, 0, (size_t)NTEST*4 + 256, stream);  // cnt + maxb2u
    prep <<<NTRAIN/256, 256, 0, stream>>>(x_train, xtr16, hb2, maxb2u);
    prepT<<<NTEST/256,  256, 0, stream>>>(x_test, xtst16, a2);
    pre_kernel<<<NTEST/16, 256, 0, stream>>>(xtr16, xtst16, hb2, a2, maxb2u,
                                             Tfp, thrW);
    knnA<<<1024, 256, 0, stream>>>(xtr16, xtst16, hb2, thrW, cnt, cand);
    knnB<<<NTEST, 256, 0, stream>>>(x_train, hb2, x_test, y_train, w_train,
                                    Tfp, cnt, cand, out);
  } else {
    knn_legacy<<<NTEST, 256, 0, stream>>>(x_train, x_test, y_train, w_train, out);
  }
}

// Round 5
// 424.522 us; speedup vs baseline: 1.9640x; 1.9640x over previous
//
#include <hip/hip_runtime.h>

#define NTRAIN 32768
#define NTEST  4096
#define DIM    64
#define KSEL   32
#define NLAB   1000
#define SAMPLE 2048
#define PRANK  16
#define CAP    960
#define POOLCAP 1600
#define WCOEF  0.02f   // >= 2^-8 bf16-rounding bound * 5x safety

using short8 = __attribute__((ext_vector_type(8))) short;
using f32x4  = __attribute__((ext_vector_type(4))) float;
typedef unsigned short u16;

// monotone float -> uint mapping (preserves total order incl. negatives)
__device__ __forceinline__ unsigned f2u(float f){
  unsigned b = __float_as_uint(f);
  return (b & 0x80000000u) ? ~b : (b | 0x80000000u);
}
__device__ __forceinline__ float u2f(unsigned u){
  unsigned b = (u & 0x80000000u) ? (u & 0x7fffffffu) : ~u;
  return __uint_as_float(b);
}
// fp32 -> bf16 round-to-nearest-even
__device__ __forceinline__ u16 f2b(float x){
  unsigned u = __float_as_uint(x);
  return (u16)((u + 0x7fffu + ((u >> 16) & 1u)) >> 16);
}

struct Sel {
  unsigned hist[2048];
  unsigned wsum[4];
  unsigned sB, sLess, sU;
  int sNeed;
};

// exact value of the rank-th smallest key (1-based) among keys[0..n). n>=rank.
__device__ unsigned radix_select(const unsigned* __restrict__ keys, int n,
                                 unsigned rank, Sel* s, int t, int* needOut)
{
  const int lane = t & 63, wid = t >> 6;
  unsigned target = rank, pref = 0;
  for (int lev = 0; lev < 3; ++lev){
    const int nb    = (lev == 2) ? 1024 : 2048;
    const int shift = (lev == 0) ? 21 : (lev == 1 ? 10 : 0);
    for (int q = t; q < nb; q += 256) s->hist[q] = 0;
    __syncthreads();
    for (int i = t; i < n; i += 256){
      unsigned u = keys[i];
      bool ok = (lev == 0) ? true
              : (lev == 1) ? ((u >> 21) == pref)
                           : ((u >> 10) == pref);
      if (ok) atomicAdd(&s->hist[(u >> shift) & (unsigned)(nb - 1)], 1u);
    }
    __syncthreads();
    const int g = nb / 256;
    unsigned sl = 0;
#pragma unroll
    for (int k = 0; k < 8; ++k) if (k < g) sl += s->hist[t*g + k];
    unsigned x = sl;
#pragma unroll
    for (int ofs = 1; ofs < 64; ofs <<= 1){
      unsigned v = __shfl_up(x, (unsigned)ofs, 64);
      if (lane >= ofs) x += v;
    }
    if (lane == 63) s->wsum[wid] = x;
    __syncthreads();
    unsigned woff = 0;
#pragma unroll
    for (int w = 0; w < 4; ++w) if (w < wid) woff += s->wsum[w];
    unsigned incl = x + woff;
    unsigned excl = incl - sl;
    if (excl < target && target <= incl){
      unsigned cum = excl; int b = t*g;
      while (cum + s->hist[b] < target){ cum += s->hist[b]; ++b; }
      s->sB = (unsigned)b; s->sLess = cum;
    }
    __syncthreads();
    unsigned B = s->sB, cl = s->sLess;
    target -= cl;
    if      (lev == 0) pref = B;
    else if (lev == 1) pref = (pref << 11) | B;
    else if (t == 0){ s->sU = (pref << 10) | B; s->sNeed = (int)target; }
  }
  __syncthreads();
  *needOut = s->sNeed;
  return s->sU;
}

// exact top-KSEL among (ku,ki)[0..n) by (key asc, idx asc). n>=KSEL. writes selI.
__device__ void select32(const unsigned* ku, const unsigned* ki, int n,
                         Sel* s, unsigned* tieI, unsigned* selI,
                         int* selCnt, int* tieCnt, int t)
{
  int need;
  unsigned ustar = radix_select(ku, n, KSEL, s, t, &need);
  if (t == 0){ *selCnt = 0; *tieCnt = 0; }
  __syncthreads();
  for (int i = t; i < n; i += 256){
    unsigned u = ku[i];
    if (u < ustar){ int p = atomicAdd(selCnt, 1); if (p < 40) selI[p] = ki[i]; }
    else if (u == ustar){ int p = atomicAdd(tieCnt, 1); if (p < 256) tieI[p] = ki[i]; }
  }
  __syncthreads();
  int nT = *tieCnt; if (nT > 256) nT = 256;
  if (t < nT){
    unsigned my = tieI[t]; int r = 0;
    for (int k = 0; k < nT; ++k) r += (tieI[k] < my) ? 1 : 0;
    if (r < need){ int p = atomicAdd(selCnt, 1); if (p < 40) selI[p] = my; }
  }
  __syncthreads();
}

// ---- calib: measure the MFMA output-slot -> (A-index, B-index) mapping ----
// Probe 1: A[v][k]=v+1, B=1  -> D slot value = 32*(M+1) recovers A-index M.
// Probe 2: A=1, B[v][k]=v+1  -> recovers B-index J.
// Probe 3: A=B=k-pattern     -> sum == 11440 iff A/B k-mappings agree
//          (rearrangement-inequality equality condition).
__global__ void calib(int* __restrict__ MT, int* __restrict__ JT,
                      int* __restrict__ okf)
{
  const int l = threadIdx.x;          // 64 threads = 1 wave
  const int v = l & 15;
  short8 av, onev, kv;
  u16 vb  = f2b((float)(v + 1));
  u16 one = (u16)0x3F80;              // 1.0 bf16
#pragma unroll
  for (int e = 0; e < 8; ++e){
    ((u16*)&av)[e]   = vb;
    ((u16*)&onev)[e] = one;
    ((u16*)&kv)[e]   = f2b((float)((l >> 4)*8 + e + 1));   // 1..32, bf16-exact
  }
  f32x4 dA = {0,0,0,0}, dB = {0,0,0,0}, dK = {0,0,0,0};
  dA = __builtin_amdgcn_mfma_f32_16x16x32_bf16(av, onev, dA, 0,0,0);
  dB = __builtin_amdgcn_mfma_f32_16x16x32_bf16(onev, av, dB, 0,0,0);
  dK = __builtin_amdgcn_mfma_f32_16x16x32_bf16(kv, kv, dK, 0,0,0);
  bool ok = true;
#pragma unroll
  for (int e = 0; e < 4; ++e){
    int mi = (int)(dA[e]*(1.0f/32.0f) + 0.5f) - 1;
    int ji = (int)(dB[e]*(1.0f/32.0f) + 0.5f) - 1;
    if (mi < 0 || mi > 15 || dA[e] != 32.0f*(float)(mi+1)) ok = false;
    if (ji < 0 || ji > 15 || dB[e] != 32.0f*(float)(ji+1)) ok = false;
    if (dK[e] != 11440.0f) ok = false;   // sum_{k=1..32} k^2, fp32-exact
    MT[l*4 + e] = mi & 15;
    JT[l*4 + e] = ji & 15;
  }
  unsigned long long bal = __ballot(ok);
  if (l == 0) okf[0] = (bal == ~0ull) ? 1 : 0;
}

// ---- prep: x_train -> bf16 row-major + hb2 = 0.5*||b||^2 + max b2 ----
__global__ __launch_bounds__(256) void prep(const float* __restrict__ xtr,
        u16* __restrict__ xtr16, float* __restrict__ hb2,
        unsigned* __restrict__ maxb2u)
{
  int j = blockIdx.x*256 + threadIdx.x;
  const float4* rp = (const float4*)(xtr + (size_t)j*DIM);
  u16* orow = xtr16 + (size_t)j*DIM;
  float s = 0.f;
#pragma unroll
  for (int q = 0; q < 16; ++q){
    float4 w = rp[q];
    uint2 pk;
    pk.x = (unsigned)f2b(w.x) | ((unsigned)f2b(w.y) << 16);
    pk.y = (unsigned)f2b(w.z) | ((unsigned)f2b(w.w) << 16);
    *(uint2*)(orow + q*4) = pk;
    s = fmaf(w.x,w.x,s); s = fmaf(w.y,w.y,s);
    s = fmaf(w.z,w.z,s); s = fmaf(w.w,w.w,s);
  }
  hb2[j] = 0.5f * s;
  atomicMax(maxb2u, __float_as_uint(s));   // s > 0 -> uint order == float order
}

// ---- prepT: x_test -> bf16 row-major + a2 ----
__global__ __launch_bounds__(256) void prepT(const float* __restrict__ xtst,
        u16* __restrict__ xtst16, float* __restrict__ a2)
{
  int m = blockIdx.x*256 + threadIdx.x;
  const float4* rp = (const float4*)(xtst + (size_t)m*DIM);
  u16* orow = xtst16 + (size_t)m*DIM;
  float s = 0.f;
#pragma unroll
  for (int q = 0; q < 16; ++q){
    float4 w = rp[q];
    uint2 pk;
    pk.x = (unsigned)f2b(w.x) | ((unsigned)f2b(w.y) << 16);
    pk.y = (unsigned)f2b(w.z) | ((unsigned)f2b(w.w) << 16);
    *(uint2*)(orow + q*4) = pk;
    s = fmaf(w.x,w.x,s); s = fmaf(w.y,w.y,s);
    s = fmaf(w.z,w.z,s); s = fmaf(w.w,w.w,s);
  }
  a2[m] = s;
}

// ---- pre: per-test threshold via MFMA keys over first SAMPLE train pts ----
__global__ __launch_bounds__(256) void pre_kernel(const u16* __restrict__ xtr16,
        const u16* __restrict__ xtst16, const float* __restrict__ hb2,
        const float* __restrict__ a2, const unsigned* __restrict__ maxb2u,
        const int* __restrict__ MT, const int* __restrict__ JT,
        const int* __restrict__ okf,
        float* __restrict__ Tfp, float* __restrict__ thrW)
{
  __shared__ unsigned keysL[8][SAMPLE+4];
  __shared__ Sel ss;

  const int t = threadIdx.x, lane = t & 63, w = t >> 6;
  const int m0 = blockIdx.x * 16;
  const int oprow = lane & 15, kgrp = lane >> 4;

  if (okf[0] == 0){
    if (t < 16){ Tfp[m0 + t] = 0.f; thrW[m0 + t] = -1e30f; }
    return;
  }

  int Ml[4], Jl[4];
#pragma unroll
  for (int e = 0; e < 4; ++e){ Ml[e] = MT[lane*4+e]; Jl[e] = JT[lane*4+e]; }

  const u16* ap = xtst16 + (size_t)(m0 + oprow)*DIM + kgrp*8;
  short8 af0 = *(const short8*)ap;
  short8 af1 = *(const short8*)(ap + 32);
  const float mb = __uint_as_float(*maxb2u);

  for (int ph = 0; ph < 2; ++ph){
    __syncthreads();
    for (int jt = 0; jt < SAMPLE/64; ++jt){
      int j0 = w*(SAMPLE/4) + jt*16;
      const u16* bp = xtr16 + (size_t)(j0 + oprow)*DIM + kgrp*8;
      short8 b0 = *(const short8*)bp;
      short8 b1 = *(const short8*)(bp + 32);
      f32x4 acc = {0.f,0.f,0.f,0.f};
      acc = __builtin_amdgcn_mfma_f32_16x16x32_bf16(af0, b0, acc, 0,0,0);
      acc = __builtin_amdgcn_mfma_f32_16x16x32_bf16(af1, b1, acc, 0,0,0);
#pragma unroll
      for (int r = 0; r < 4; ++r){
        int row = Ml[r];                 // measured test index within tile
        if ((row >> 3) == ph){
          int col = j0 + Jl[r];          // measured train index
          keysL[row & 7][col] = f2u(hb2[col] - acc[r]);
        }
      }
    }
    __syncthreads();
    for (int r = 0; r < 8; ++r){
      int need;
      unsigned ustar = radix_select(&keysL[r][0], SAMPLE, PRANK, &ss, t, &need);
      if (t == 0){
        int m = m0 + ph*8 + r;
        float Tf = u2f(ustar);
        Tfp[m]  = Tf;
        thrW[m] = Tf + WCOEF * sqrtf(a2[m] * mb);
      }
    }
  }
}

// ---- kernel A: MFMA filter, table-driven indexing, no LDS/barriers in loop ----
__global__ __launch_bounds__(256, 4) void knnA(const u16* __restrict__ xtr16,
        const u16* __restrict__ xtst16, const float* __restrict__ hb2,
        const float* __restrict__ thrW, const int* __restrict__ MT,
        const int* __restrict__ JT, const int* __restrict__ okf,
        unsigned* __restrict__ cnt, unsigned* __restrict__ cand)
{
  if (okf[0] == 0) return;
  const int t = threadIdx.x, lane = t & 63, w = t >> 6;
  const int bid = blockIdx.x;
  const int jc  = bid & 31;           // 32 j-chunks of 1024
  const int mg  = bid >> 5;           // 32 m-blocks of 128 tests
  const int m0  = mg*128 + w*32;      // wave owns 32 tests (2 MFMA subtiles)
  const int oprow = lane & 15, kgrp = lane >> 4;

  int Ml[4], Jl[4];
#pragma unroll
  for (int e = 0; e < 4; ++e){ Ml[e] = MT[lane*4+e]; Jl[e] = JT[lane*4+e]; }

  const u16* ap = xtst16 + (size_t)(m0 + oprow)*DIM + kgrp*8;
  short8 a00 = *(const short8*)ap;
  short8 a01 = *(const short8*)(ap + 32);
  short8 a10 = *(const short8*)(ap + 16*DIM);
  short8 a11 = *(const short8*)(ap + 16*DIM + 32);

  float thr0[4], thr1[4];
#pragma unroll
  for (int r = 0; r < 4; ++r){
    thr0[r] = thrW[m0 + Ml[r]];
    thr1[r] = thrW[m0 + 16 + Ml[r]];
  }
  float tmax0 = fmaxf(fmaxf(thr0[0],thr0[1]), fmaxf(thr0[2],thr0[3]));
  float tmax1 = fmaxf(fmaxf(thr1[0],thr1[1]), fmaxf(thr1[2],thr1[3]));

  const u16* bp = xtr16 + (size_t)(jc*1024 + oprow)*DIM + kgrp*8;
  const float* hb = hb2 + jc*1024;

#pragma unroll 2
  for (int jt = 0; jt < 64; ++jt){
    short8 b0 = *(const short8*)bp;
    short8 b1 = *(const short8*)(bp + 32);
    float h0 = hb[Jl[0]], h1 = hb[Jl[1]], h2 = hb[Jl[2]], h3 = hb[Jl[3]];
    f32x4 c0 = {0.f,0.f,0.f,0.f}, c1 = {0.f,0.f,0.f,0.f};
    c0 = __builtin_amdgcn_mfma_f32_16x16x32_bf16(a00, b0, c0, 0,0,0);
    c0 = __builtin_amdgcn_mfma_f32_16x16x32_bf16(a01, b1, c0, 0,0,0);
    c1 = __builtin_amdgcn_mfma_f32_16x16x32_bf16(a10, b0, c1, 0,0,0);
    c1 = __builtin_amdgcn_mfma_f32_16x16x32_bf16(a11, b1, c1, 0,0,0);
    float h[4] = {h0, h1, h2, h3};
    float hmin = fminf(fminf(h0,h1), fminf(h2,h3));
    int jbase = jc*1024 + jt*16;
    // candidate iff key = hb2[j] - dot < thrW[m]  <=>  dot + thrW > hb2[j]
    float mx0 = fmaxf(fmaxf(c0[0],c0[1]), fmaxf(c0[2],c0[3]));
    if (mx0 + tmax0 > hmin){
#pragma unroll
      for (int r = 0; r < 4; ++r) if (c0[r] + thr0[r] > h[r]){
        int m = m0 + Ml[r];
        unsigned p = atomicAdd(&cnt[m], 1u);
        if (p < CAP) cand[(size_t)m*CAP + p] = (unsigned)(jbase + Jl[r]);
      }
    }
    float mx1 = fmaxf(fmaxf(c1[0],c1[1]), fmaxf(c1[2],c1[3]));
    if (mx1 + tmax1 > hmin){
#pragma unroll
      for (int r = 0; r < 4; ++r) if (c1[r] + thr1[r] > h[r]){
        int m = m0 + 16 + Ml[r];
        unsigned p = atomicAdd(&cnt[m], 1u);
        if (p < CAP) cand[(size_t)m*CAP + p] = (unsigned)(jbase + Jl[r]);
      }
    }
    bp += 16*DIM; hb += 16;
  }
}

// ---- kernel B: exact fp32 re-rank of candidates with verification ----
__global__ __launch_bounds__(256) void knnB(const float* __restrict__ x_train,
        const float* __restrict__ hb2, const float* __restrict__ x_test,
        const int* __restrict__ y_train, const float* __restrict__ w_train,
        const float* __restrict__ Tfp, const unsigned* __restrict__ cnt,
        const unsigned* __restrict__ cand, int* __restrict__ out)
{
  __shared__ unsigned ku[POOLCAP], ki[POOLCAP];
  __shared__ unsigned chunkKeys[1024];
  __shared__ Sel ss;
  __shared__ unsigned tieI[256];
  __shared__ unsigned selI[40];
  __shared__ int selCnt, tieCnt, poolCnt, nBelow;
  __shared__ float votes[NLAB];

  const int t = threadIdx.x, m = blockIdx.x;
  float a[DIM];
  const float4* am = (const float4*)(x_test + (size_t)m*DIM);
#pragma unroll
  for (int q = 0; q < 16; ++q){
    float4 v = am[q];
    a[4*q]=v.x; a[4*q+1]=v.y; a[4*q+2]=v.z; a[4*q+3]=v.w;
  }
  const float Tf = Tfp[m];
  const unsigned c = cnt[m];

  if (t == 0) nBelow = 0;
  __syncthreads();

  bool ok = false;
  if (c >= KSEL && c <= CAP){
    for (int i = t; i < (int)c; i += 256){
      unsigned j = cand[(size_t)m*CAP + i];
      const float4* rp = (const float4*)(x_train + (size_t)j*DIM);
      float s = 0.f;
#pragma unroll
      for (int q = 0; q < 16; ++q){
        float4 v = rp[q];
        s = fmaf(a[4*q],v.x,s); s = fmaf(a[4*q+1],v.y,s);
        s = fmaf(a[4*q+2],v.z,s); s = fmaf(a[4*q+3],v.w,s);
      }
      float kf = hb2[j] - s;
      ku[i] = f2u(kf); ki[i] = j;
      if (kf < Tf) atomicAdd(&nBelow, 1);
    }
    __syncthreads();
    ok = (nBelow >= KSEL);   // guarantees global top-32 is inside candidates
    if (ok) select32(ku, ki, (int)c, &ss, tieI, selI, &selCnt, &tieCnt, t);
  }

  if (!ok){
    // exact full scan (safety net): chunk top-32 pooling
    if (t == 0) poolCnt = 0;
    __syncthreads();
    for (int ch = 0; ch < NTRAIN/1024; ++ch){
      const int j0 = ch*1024;
      for (int q = 0; q < 4; ++q){
        int j = j0 + q*256 + t;
        const float4* rp = (const float4*)(x_train + (size_t)j*DIM);
        float s = 0.f;
#pragma unroll
        for (int qq = 0; qq < 16; ++qq){
          float4 v = rp[qq];
          s = fmaf(a[4*qq],v.x,s); s = fmaf(a[4*qq+1],v.y,s);
          s = fmaf(a[4*qq+2],v.z,s); s = fmaf(a[4*qq+3],v.w,s);
        }
        chunkKeys[q*256 + t] = f2u(hb2[j] - s);
      }
      __syncthreads();
      int need;
      unsigned ustar = radix_select(chunkKeys, 1024, KSEL, &ss, t, &need);
      for (int q = 0; q < 4; ++q){
        unsigned u = chunkKeys[q*256 + t];
        if (u <= ustar){
          int p = atomicAdd(&poolCnt, 1);
          if (p < POOLCAP){ ku[p] = u; ki[p] = (unsigned)(j0 + q*256 + t); }
        }
      }
      __syncthreads();
    }
    int n = poolCnt; if (n > POOLCAP) n = POOLCAP;
    select32(ku, ki, n, &ss, tieI, selI, &selCnt, &tieCnt, t);
  }

  // weighted vote over 1000 labels
  for (int q = t; q < NLAB; q += 256) votes[q] = 0.f;
  __syncthreads();
  int nSel = selCnt; if (nSel > KSEL) nSel = KSEL;
  if (t < nSel){
    unsigned j = selI[t];
    atomicAdd(&votes[y_train[j]], w_train[j]);
  }
  __syncthreads();

  // argmax, lowest label wins ties
  float* rv = (float*)ss.hist;
  int*   rl = (int*)(ss.hist + 256);
  float bv = -1.f; int bl = 0;
  for (int l = t; l < NLAB; l += 256){
    float v = votes[l];
    if (v > bv){ bv = v; bl = l; }
  }
  rv[t] = bv; rl[t] = bl;
  __syncthreads();
  for (int sred = 128; sred > 0; sred >>= 1){
    if (t < sred){
      if (rv[t+sred] > rv[t] || (rv[t+sred] == rv[t] && rl[t+sred] < rl[t])){
        rv[t] = rv[t+sred]; rl[t] = rl[t+sred];
      }
    }
    __syncthreads();
  }
  if (t == 0) out[m] = rl[0];
}

// ---- legacy (direct-read path): used only if ws too small ----
__global__ __launch_bounds__(256) void knn_legacy(
    const float* __restrict__ x_train, const float* __restrict__ x_test,
    const int* __restrict__ y_train, const float* __restrict__ w_train,
    int* __restrict__ out)
{
  __shared__ unsigned keys[16384];
  __shared__ Sel ss;
  __shared__ unsigned candU[64];
  __shared__ unsigned candI[64];
  __shared__ unsigned tieI[256];
  __shared__ int nCand, nTie;
  __shared__ float rv[256]; __shared__ int rl[256];

  float* votes = (float*)ss.hist;
  const int t = threadIdx.x;
  const int m = blockIdx.x;

  float a[DIM];
  const float* am = x_test + (size_t)m * DIM;
#pragma unroll
  for (int d = 0; d < DIM; ++d) a[d] = am[d];

  if (t == 0) nCand = 0;

  for (int h = 0; h < 2; ++h){
    __syncthreads();
    for (int i = 0; i < 64; ++i){
      int j = h*16384 + i*256 + t;
      const float4* bp = (const float4*)(x_train + (size_t)j * DIM);
      float s = 0.f;
#pragma unroll
      for (int q = 0; q < 16; ++q){
        float4 v = bp[q];
        float e0 = a[4*q]   - v.x, e1 = a[4*q+1] - v.y;
        float e2 = a[4*q+2] - v.z, e3 = a[4*q+3] - v.w;
        s = fmaf(e0,e0,s); s = fmaf(e1,e1,s); s = fmaf(e2,e2,s); s = fmaf(e3,e3,s);
      }
      keys[i*256 + t] = f2u(s);
    }
    __syncthreads();

    int need;
    unsigned ustar = radix_select(keys, 16384, KSEL, &ss, t, &need);
    if (t == 0) nTie = 0;
    __syncthreads();

    for (int i = 0; i < 64; ++i){
      unsigned u   = keys[i*256 + t];
      unsigned idx = (unsigned)(h*16384 + i*256 + t);
      if (u < ustar){
        int p = atomicAdd(&nCand, 1);
        if (p < 64){ candU[p] = u; candI[p] = idx; }
      } else if (u == ustar){
        int p = atomicAdd(&nTie, 1);
        if (p < 256) tieI[p] = idx;
      }
    }
    __syncthreads();
    int nT = nTie; if (nT > 256) nT = 256;
    if (t < nT){
      unsigned my = tieI[t]; int r = 0;
      for (int k = 0; k < nT; ++k) r += (tieI[k] < my) ? 1 : 0;
      if (r < need){
        int p = atomicAdd(&nCand, 1);
        if (p < 64){ candU[p] = ustar; candI[p] = my; }
      }
    }
    __syncthreads();
  }

  for (int q = t; q < NLAB; q += 256) votes[q] = 0.f;
  __syncthreads();
  int nC = nCand; if (nC > 64) nC = 64;
  if (t < nC){
    unsigned mu = candU[t], mi = candI[t];
    int r = 0;
    for (int k = 0; k < nC; ++k){
      unsigned kku = candU[k], kki = candI[k];
      r += (kku < mu || (kku == mu && kki < mi)) ? 1 : 0;
    }
    if (r < KSEL){
      int lab = y_train[mi];
      atomicAdd(&votes[lab], w_train[mi]);
    }
  }
  __syncthreads();

  float bv = -1.f; int bl = 0;
  for (int l = t; l < NLAB; l += 256){
    float v = votes[l];
    if (v > bv){ bv = v; bl = l; }
  }
  rv[t] = bv; rl[t] = bl;
  __syncthreads();
  for (int s = 128; s > 0; s >>= 1){
    if (t < s){
      if (rv[t+s] > rv[t] || (rv[t+s] == rv[t] && rl[t+s] < rl[t])){
        rv[t] = rv[t+s]; rl[t] = rl[t+s];
      }
    }
    __syncthreads();
  }
  if (t == 0) out[m] = rl[0];
}

extern "C" void kernel_launch(void* const* d_in, const int* in_sizes, int n_in,
                              void* d_out, int out_size, void* d_ws, size_t ws_size,
                              hipStream_t stream)
{
  (void)in_sizes; (void)n_in; (void)out_size;
  const float* x_train = (const float*)d_in[0];
  const int*   y_train = (const int*)  d_in[1];
  const float* x_test  = (const float*)d_in[2];
  const float* w_train = (const float*)d_in[3];
  int* out = (int*)d_out;

  char* p = (char*)d_ws;
  u16*      xtr16  = (u16*)p;       p += (size_t)NTRAIN*DIM*2;
  u16*      xtst16 = (u16*)p;       p += (size_t)NTEST*DIM*2;
  float*    hb2    = (float*)p;     p += (size_t)NTRAIN*4;
  float*    a2     = (float*)p;     p += (size_t)NTEST*4;
  float*    Tfp    = (float*)p;     p += (size_t)NTEST*4;
  float*    thrW   = (float*)p;     p += (size_t)NTEST*4;
  unsigned* cnt    = (unsigned*)p;  p += (size_t)NTEST*4;
  unsigned* maxb2u = (unsigned*)p;  p += 256;
  int*      MT     = (int*)p;       p += 64*4*4;
  int*      JT     = (int*)p;       p += 64*4*4;
  int*      okf    = (int*)p;       p += 256;
  unsigned* cand   = (unsigned*)p;  p += (size_t)NTEST*CAP*4;
  size_t need = (size_t)(p - (char*)d_ws);

  if (ws_size >= need){
    hipMemsetAsync(cnt, 0, (size_t)NTEST*4 + 256, stream);  // cnt + maxb2u
    calib<<<1, 64, 0, stream>>>(MT, JT, okf);
    prep <<<NTRAIN/256, 256, 0, stream>>>(x_train, xtr16, hb2, maxb2u);
    prepT<<<NTEST/256,  256, 0, stream>>>(x_test, xtst16, a2);
    pre_kernel<<<NTEST/16, 256, 0, stream>>>(xtr16, xtst16, hb2, a2, maxb2u,
                                             MT, JT, okf, Tfp, thrW);
    knnA<<<1024, 256, 0, stream>>>(xtr16, xtst16, hb2, thrW, MT, JT, okf,
                                   cnt, cand);
    knnB<<<NTEST, 256, 0, stream>>>(x_train, hb2, x_test, y_train, w_train,
                                    Tfp, cnt, cand, out);
  } else {
    knn_legacy<<<NTEST, 256, 0, stream>>>(x_train, x_test, y_train, w_train, out);
  }
}